// Round 13
// baseline (46.836 us; speedup 1.0000x reference)
//
#include <hip/hip_runtime.h>

// ISTFT via FFT, two-frames-per-transform pack, TWO packs per block (ILP-2):
//   frames[b,t,n] = Re{ sum_k X_t[k] e^{+2pi i kn/1024} } * hann[n]/1024
// Pack Z[k] = X_{2m}[k] + i*X_{2m+1}[k] -> one 1024-pt complex inverse FFT gives
// frame 2m = Re z, frame 2m+1 = Im z. im[k=0]/im[k=512] ZEROED when packing
// (they contribute 0 to the reference; leaking them across the pack was the
// round-9 failure). Block processes packs A (rows r0,r0+1) and B (rows r0+2,
// r0+3) with shared stage addressing/twiddles -> per-FFT barriers and twiddle
// loads halved, dual butterflies give ILP-2 to hide LDS latency.
// Stockham stage rule (proven r12): read tid+256k, write 4Sp+q+Sk; last stage
// S=256 (p=0) writes tid+256k with unit twiddles.

#define BATCH    8
#define NFRAMES  2048
#define FREQ     513
#define OUTCOLS  524032
#define FRAMES_B ((size_t)16384 * 1024 * 2)    // 32 MB bf16 frames
#define TW_OFF   FRAMES_B
#define WS_NEED  (FRAMES_B + 1024 * 8)

#define PD(a) ((a) + ((a) >> 4))               // pad 1 f32x2 per 16

typedef __attribute__((ext_vector_type(2))) float f32x2;
typedef __attribute__((ext_vector_type(4))) float f32x4;
typedef __attribute__((ext_vector_type(2))) unsigned uint2v;

__device__ __forceinline__ unsigned short f2bf(float x) {
    unsigned u = __float_as_uint(x);
    return (unsigned short)((u + 0x7fffu + ((u >> 16) & 1u)) >> 16);
}
__device__ __forceinline__ unsigned pack2(float x, float y) {
    return (unsigned)f2bf(x) | ((unsigned)f2bf(y) << 16);
}

// ================= kernel 0: twiddle table =================
__global__ __launch_bounds__(256) void twiddle_prep(float* __restrict__ tw) {
    int k = blockIdx.x * 256 + threadIdx.x;    // 0..1023
    float s, c;
    sincosf(6.283185307179586f * (float)k * (1.0f / 1024.0f), &s, &c);
    ((f32x2*)tw)[k] = (f32x2){c, s};
}

// ================= kernel 1: dual 1024-pt IFFT (4 frames) per block =================
__global__ __launch_bounds__(256) void ifft_frames4(
    const float* __restrict__ re, const float* __restrict__ im,
    const float* __restrict__ ola, const float* __restrict__ twg,
    unsigned short* __restrict__ frames) {
    __shared__ f32x2 XA[1088], YA[1088], XB[1088], YB[1088];

    const int r0  = blockIdx.x * 4;    // 4 consecutive frame rows
    const int tid = threadIdx.x;
    const f32x2* tw = (const f32x2*)twg;

    // ---- load both packs: Z[k]=X1+iX2, hermitian mirrors, DC/Nyq imag zeroed ----
#pragma unroll
    for (int P = 0; P < 2; ++P) {
        f32x2* X = P ? XB : XA;
        const float* fre0 = re + (size_t)(r0 + 2 * P) * FREQ;
        const float* fim0 = im + (size_t)(r0 + 2 * P) * FREQ;
        const float* fre1 = fre0 + FREQ;
        const float* fim1 = fim0 + FREQ;
#pragma unroll
        for (int h = 0; h < 2; ++h) {
            int k = tid + 256 * h;
            float a1 = fre0[k], b1 = fim0[k];
            float a2 = fre1[k], b2 = fim1[k];
            if (k == 0) { b1 = 0.0f; b2 = 0.0f; }
            X[PD(k)] = (f32x2){a1 - b2, b1 + a2};
            if (k > 0) X[PD(1024 - k)] = (f32x2){a1 + b2, a2 - b1};
        }
        if (tid == 0) X[PD(512)] = (f32x2){fre0[512], fre1[512]};
    }
    __syncthreads();

#define CBFLY(A, B, C, D, WARR)                                               \
    {                                                                         \
        float apcr = A[0] + C[0], apci = A[1] + C[1];                         \
        float amcr = A[0] - C[0], amci = A[1] - C[1];                         \
        float bpdr = B[0] + D[0], bpdi = B[1] + D[1];                         \
        float jbr  = -(B[1] - D[1]), jbi = (B[0] - D[0]);   /* i*(b-d) */     \
        WARR[PD(wb)] = (f32x2){apcr + bpdr, apci + bpdi};                     \
        float u1r = amcr + jbr, u1i = amci + jbi;                             \
        WARR[PD(wb + S_)]     = (f32x2){u1r * w1[0] - u1i * w1[1],            \
                                        u1r * w1[1] + u1i * w1[0]};           \
        float u2r = apcr - bpdr, u2i = apci - bpdi;                           \
        WARR[PD(wb + 2 * S_)] = (f32x2){u2r * w2[0] - u2i * w2[1],            \
                                        u2r * w2[1] + u2i * w2[0]};           \
        float u3r = amcr - jbr, u3i = amci - jbi;                             \
        WARR[PD(wb + 3 * S_)] = (f32x2){u3r * w3[0] - u3i * w3[1],            \
                                        u3r * w3[1] + u3i * w3[0]};           \
    }

#define STAGE(S, RA, WA, RB, WB)                                              \
    {                                                                         \
        const int S_ = (S);                                                   \
        const int p  = tid / S_;                                              \
        const int q  = tid - p * S_;                                          \
        const int t1 = p * S_;                                                \
        const f32x2 w1 = tw[t1], w2 = tw[2 * t1], w3 = tw[3 * t1];            \
        const int wb = 4 * S_ * p + q;                                        \
        f32x2 aA = RA[PD(tid)],       bA = RA[PD(tid + 256)];                 \
        f32x2 cA = RA[PD(tid + 512)], dA = RA[PD(tid + 768)];                 \
        f32x2 aB = RB[PD(tid)],       bB = RB[PD(tid + 256)];                 \
        f32x2 cB = RB[PD(tid + 512)], dB = RB[PD(tid + 768)];                 \
        CBFLY(aA, bA, cA, dA, WA);                                            \
        CBFLY(aB, bB, cB, dB, WB);                                            \
        __syncthreads();                                                      \
    }

#define LBFLY(A, B, C, D, WARR)                                               \
    {                                                                         \
        float apcr = A[0] + C[0], apci = A[1] + C[1];                         \
        float amcr = A[0] - C[0], amci = A[1] - C[1];                         \
        float bpdr = B[0] + D[0], bpdi = B[1] + D[1];                         \
        float jbr  = -(B[1] - D[1]), jbi = (B[0] - D[0]);                     \
        WARR[PD(tid)]       = (f32x2){apcr + bpdr, apci + bpdi};              \
        WARR[PD(tid + 256)] = (f32x2){amcr + jbr, amci + jbi};                \
        WARR[PD(tid + 512)] = (f32x2){apcr - bpdr, apci - bpdi};              \
        WARR[PD(tid + 768)] = (f32x2){amcr - jbr, amci - jbi};                \
    }

    STAGE(1,  XA, YA, XB, YB)    // n = 1024
    STAGE(4,  YA, XA, YB, XB)    // n = 256
    STAGE(16, XA, YA, XB, YB)    // n = 64
    STAGE(64, YA, XA, YB, XB)    // n = 16
    {  // S = 256: p = 0 -> unit twiddles; writes out[tid + 256*k]
        f32x2 aA = XA[PD(tid)],       bA = XA[PD(tid + 256)];
        f32x2 cA = XA[PD(tid + 512)], dA = XA[PD(tid + 768)];
        f32x2 aB = XB[PD(tid)],       bB = XB[PD(tid + 256)];
        f32x2 cB = XB[PD(tid + 512)], dB = XB[PD(tid + 768)];
        LBFLY(aA, bA, cA, dA, YA);
        LBFLY(aB, bB, cB, dB, YB);
        __syncthreads();
    }
#undef STAGE
#undef CBFLY
#undef LBFLY

    // frames: row r0 = Re zA, r0+1 = Im zA, r0+2 = Re zB, r0+3 = Im zB; *hann/1024
    const float inv = 1.0f / 1024.0f;
    unsigned* f0 = (unsigned*)frames + (size_t)r0 * 512;
#pragma unroll
    for (int h = 0; h < 2; ++h) {
        int n = 2 * tid + 512 * h;
        f32x2 o  = *(const f32x2*)(ola + n);
        float s0 = sqrtf(o[0]) * inv, s1 = sqrtf(o[1]) * inv;
        f32x2 zA0 = YA[PD(n)], zA1 = YA[PD(n + 1)];
        f32x2 zB0 = YB[PD(n)], zB1 = YB[PD(n + 1)];
        int c = tid + 256 * h;
        f0[c]        = pack2(zA0[0] * s0, zA1[0] * s1);
        f0[c + 512]  = pack2(zA0[1] * s0, zA1[1] * s1);
        f0[c + 1024] = pack2(zB0[0] * s0, zB1[0] * s1);
        f0[c + 1536] = pack2(zB0[1] * s0, zB1[1] * s1);
    }
}

// ================= kernel 2: OLA gather, 4 samples/thread =================
__global__ __launch_bounds__(256) void ola_fold4(
    const unsigned short* __restrict__ frames, const float* __restrict__ ola,
    float* __restrict__ out) {
    const int col0 = (blockIdx.x * 256 + threadIdx.x) * 4;
    if (col0 >= OUTCOLS) return;
    const int b  = blockIdx.y;
    const int s  = col0 + 512;     // uncropped sample index
    const int g  = s >> 8;
    const int ls = s & 255;        // multiple of 4

    float a0 = 0.f, a1 = 0.f, a2 = 0.f, a3 = 0.f;
    float w0 = 0.f, w1 = 0.f, w2 = 0.f, w3 = 0.f;
#pragma unroll
    for (int j = 0; j < 4; ++j) {
        const int t = g - j;
        if (t >= 0 && t < NFRAMES) {
            uint2v u = *(const uint2v*)(frames + (((size_t)(b * NFRAMES + t)) << 10) + ls + 256 * j);
            a0 += __uint_as_float(u[0] << 16);
            a1 += __uint_as_float(u[0] & 0xffff0000u);
            a2 += __uint_as_float(u[1] << 16);
            a3 += __uint_as_float(u[1] & 0xffff0000u);
            f32x4 o = *(const f32x4*)(ola + ls + 256 * j);
            w0 += o[0]; w1 += o[1]; w2 += o[2]; w3 += o[3];
        }
    }
    f32x4 r = (f32x4){a0 / fmaxf(w0, 1e-11f), a1 / fmaxf(w1, 1e-11f),
                      a2 / fmaxf(w2, 1e-11f), a3 / fmaxf(w3, 1e-11f)};
    *(f32x4*)(out + (size_t)b * OUTCOLS + col0) = r;
}

// ================= last-resort naive fallback (round-1, proven) =================
__global__ __launch_bounds__(256) void istft_naive(
    const float* __restrict__ re, const float* __restrict__ im,
    const float* __restrict__ Wr, const float* __restrict__ Wi,
    const float* __restrict__ ola, float* __restrict__ out) {
    const int g = blockIdx.x + 2, b = blockIdx.y, ls = threadIdx.x;
    __shared__ float s_fr[4][FREQ];
    __shared__ float s_fi[4][FREQ];
#pragma unroll
    for (int jj = 0; jj < 4; ++jj) {
        const int t = g - jj;
        const bool valid = (t >= 0 && t < NFRAMES);
        const size_t base = ((size_t)b * NFRAMES + (valid ? t : 0)) * FREQ;
        for (int k = ls; k < FREQ; k += 256) {
            const float f = (k == 0 || k == FREQ - 1) ? 1.0f : 2.0f;
            s_fr[jj][k] = valid ? re[base + k] * f : 0.0f;
            s_fi[jj][k] = valid ? im[base + k] * f : 0.0f;
        }
    }
    __syncthreads();
    const float* wr = Wr + ls;
    const float* wi = Wi + ls;
    float acc = 0.0f;
    for (int k = 0; k < FREQ; ++k) {
        const float* wrk = wr + (size_t)k * 1024;
        const float* wik = wi + (size_t)k * 1024;
#pragma unroll
        for (int jj = 0; jj < 4; ++jj) {
            acc = fmaf(wrk[jj * 256], s_fr[jj][k], acc);
            acc = fmaf(-wik[jj * 256], s_fi[jj][k], acc);
        }
    }
    float wsv = 0.0f;
#pragma unroll
    for (int jj = 0; jj < 4; ++jj) {
        const int t = g - jj;
        if (t >= 0 && t < NFRAMES) wsv += ola[ls + jj * 256];
    }
    wsv = fmaxf(wsv, 1e-11f);
    out[(size_t)b * OUTCOLS + (g * 256 + ls - 512)] = acc / wsv;
}

extern "C" void kernel_launch(void* const* d_in, const int* in_sizes, int n_in,
                              void* d_out, int out_size, void* d_ws, size_t ws_size,
                              hipStream_t stream) {
    const float* re  = (const float*)d_in[0];
    const float* im  = (const float*)d_in[1];
    const float* Wr  = (const float*)d_in[2];
    const float* Wi  = (const float*)d_in[3];
    const float* ola = (const float*)d_in[4];
    float* out = (float*)d_out;

    if (ws_size >= WS_NEED) {
        unsigned short* frames = (unsigned short*)d_ws;
        float* tw = (float*)((char*)d_ws + TW_OFF);
        hipLaunchKernelGGL(twiddle_prep, dim3(4), dim3(256), 0, stream, tw);
        hipLaunchKernelGGL(ifft_frames4, dim3(4096), dim3(256), 0, stream,
                           re, im, ola, tw, frames);
        hipLaunchKernelGGL(ola_fold4, dim3(512, BATCH), dim3(256), 0, stream,
                           frames, ola, out);
    } else {
        dim3 grid(2047, BATCH);
        hipLaunchKernelGGL(istft_naive, grid, dim3(256), 0, stream,
                           re, im, Wr, Wi, ola, out);
    }
}

// Round 14
// 43.141 us; speedup vs baseline: 1.0856x; 1.0856x over previous
//
#include <hip/hip_runtime.h>

// ISTFT via FFT, two-frames-per-transform pack, 5-phase fused pipeline:
//   frames[b,t,n] = Re{ sum_k X_t[k] e^{+2pi i kn/1024} } * hann[n]/1024
// Pack Z[k] = X_{2m}[k] + i*X_{2m+1}[k] -> one 1024-pt complex inverse FFT gives
// frame 2m = Re z, frame 2m+1 = Im z. im[k=0]/im[k=512] ZEROED when packing
// (they contribute 0 to the reference; leaking them across the pack was the
// round-9 failure).
// Radix-4 DIF Stockham (proven r12): stage S reads idx tid+256k, writes
// 4Sp+q+Sk, twiddles tw[pS],tw[2pS],tw[3pS]; +i convention throughout.
// Round 14: stage 1 fused with hermitian global loads (no LDS X-fill phase),
// stage 5 (unit twiddles) fused with scale+ushort-store epilogue.
// 7 phases -> 5, barriers 6 -> 4, LDS ops ~50 -> 32, LDS stays 17.4KB.

#define BATCH    8
#define NFRAMES  2048
#define FREQ     513
#define OUTCOLS  524032
#define FRAMES_B ((size_t)16384 * 1024 * 2)    // 32 MB bf16 frames
#define TW_OFF   FRAMES_B
#define WS_NEED  (FRAMES_B + 1024 * 8)

#define PD(a) ((a) + ((a) >> 4))               // pad 1 f32x2 per 16

typedef __attribute__((ext_vector_type(2))) float f32x2;
typedef __attribute__((ext_vector_type(4))) float f32x4;
typedef __attribute__((ext_vector_type(2))) unsigned uint2v;

__device__ __forceinline__ unsigned short f2bf(float x) {
    unsigned u = __float_as_uint(x);
    return (unsigned short)((u + 0x7fffu + ((u >> 16) & 1u)) >> 16);
}

// ================= kernel 0: twiddle table =================
__global__ __launch_bounds__(256) void twiddle_prep(float* __restrict__ tw) {
    int k = blockIdx.x * 256 + threadIdx.x;    // 0..1023
    float s, c;
    sincosf(6.283185307179586f * (float)k * (1.0f / 1024.0f), &s, &c);
    ((f32x2*)tw)[k] = (f32x2){c, s};
}

// ================= kernel 1: 1024-pt IFFT per frame-pair, 5-phase =================
__global__ __launch_bounds__(256) void ifft_frames5(
    const float* __restrict__ re, const float* __restrict__ im,
    const float* __restrict__ ola, const float* __restrict__ twg,
    unsigned short* __restrict__ frames) {
    __shared__ f32x2 X[1088], Y[1088];

    const int r0  = blockIdx.x * 2;
    const int tid = threadIdx.x;
    const f32x2* tw = (const f32x2*)twg;

    const float* fre0 = re + (size_t)r0 * FREQ;
    const float* fim0 = im + (size_t)r0 * FREQ;
    const float* fre1 = fre0 + FREQ;
    const float* fim1 = fim0 + FREQ;

    // ---- phase 1: hermitian-packed loads + stage-1 butterfly (S=1), write Y ----
    {
        f32x2 a, b, c, d;
        // a: n = tid, direct Z = (a1-b2, b1+a2); DC (tid==0) b-zeroed
        {
            float A1 = fre0[tid], B1 = fim0[tid];
            float A2 = fre1[tid], B2 = fim1[tid];
            if (tid == 0) { B1 = 0.0f; B2 = 0.0f; }
            a = (f32x2){A1 - B2, B1 + A2};
        }
        // b: n = tid+256, direct
        {
            float A1 = fre0[tid + 256], B1 = fim0[tid + 256];
            float A2 = fre1[tid + 256], B2 = fim1[tid + 256];
            b = (f32x2){A1 - B2, B1 + A2};
        }
        // c: n = tid+512 -> mirror m = 512-tid, Z = (a1+b2, a2-b1);
        //    tid==0 gives m=512 (Nyquist): b-zeroed -> (a1, a2) exactly
        {
            int m = 512 - tid;
            float A1 = fre0[m], B1 = fim0[m];
            float A2 = fre1[m], B2 = fim1[m];
            if (tid == 0) { B1 = 0.0f; B2 = 0.0f; }
            c = (f32x2){A1 + B2, A2 - B1};
        }
        // d: n = tid+768 -> mirror m = 256-tid (1..256)
        {
            int m = 256 - tid;
            float A1 = fre0[m], B1 = fim0[m];
            float A2 = fre1[m], B2 = fim1[m];
            d = (f32x2){A1 + B2, A2 - B1};
        }
        // stage-1 butterfly: p=tid, q=0, wb=4*tid, twiddles tw[tid],tw[2tid],tw[3tid]
        float apcr = a[0] + c[0], apci = a[1] + c[1];
        float amcr = a[0] - c[0], amci = a[1] - c[1];
        float bpdr = b[0] + d[0], bpdi = b[1] + d[1];
        float jbr  = -(b[1] - d[1]), jbi = (b[0] - d[0]);   // i*(b-d)
        f32x2 w1 = tw[tid], w2 = tw[2 * tid], w3 = tw[3 * tid];
        const int wb = 4 * tid;
        Y[PD(wb)] = (f32x2){apcr + bpdr, apci + bpdi};
        float u1r = amcr + jbr, u1i = amci + jbi;
        Y[PD(wb + 1)] = (f32x2){u1r * w1[0] - u1i * w1[1], u1r * w1[1] + u1i * w1[0]};
        float u2r = apcr - bpdr, u2i = apci - bpdi;
        Y[PD(wb + 2)] = (f32x2){u2r * w2[0] - u2i * w2[1], u2r * w2[1] + u2i * w2[0]};
        float u3r = amcr - jbr, u3i = amci - jbi;
        Y[PD(wb + 3)] = (f32x2){u3r * w3[0] - u3i * w3[1], u3r * w3[1] + u3i * w3[0]};
    }
    __syncthreads();

    // ---- phases 2-4: generic Stockham stages (proven r12 macro) ----
#define STAGE(S, RB, WB)                                                      \
    {                                                                         \
        const int S_ = (S);                                                   \
        const int p  = tid / S_;                                              \
        const int q  = tid - p * S_;                                          \
        f32x2 a = RB[PD(tid)];                                                \
        f32x2 b = RB[PD(tid + 256)];                                          \
        f32x2 c = RB[PD(tid + 512)];                                          \
        f32x2 d = RB[PD(tid + 768)];                                          \
        float apcr = a[0] + c[0], apci = a[1] + c[1];                         \
        float amcr = a[0] - c[0], amci = a[1] - c[1];                         \
        float bpdr = b[0] + d[0], bpdi = b[1] + d[1];                         \
        float jbr  = -(b[1] - d[1]), jbi = (b[0] - d[0]);   /* i*(b-d) */     \
        const int t1 = p * S_;                                                \
        f32x2 w1 = tw[t1], w2 = tw[2 * t1], w3 = tw[3 * t1];                  \
        const int wb = 4 * S_ * p + q;                                        \
        WB[PD(wb)] = (f32x2){apcr + bpdr, apci + bpdi};                       \
        float u1r = amcr + jbr, u1i = amci + jbi;                             \
        WB[PD(wb + S_)]     = (f32x2){u1r * w1[0] - u1i * w1[1],              \
                                      u1r * w1[1] + u1i * w1[0]};             \
        float u2r = apcr - bpdr, u2i = apci - bpdi;                           \
        WB[PD(wb + 2 * S_)] = (f32x2){u2r * w2[0] - u2i * w2[1],              \
                                      u2r * w2[1] + u2i * w2[0]};             \
        float u3r = amcr - jbr, u3i = amci - jbi;                             \
        WB[PD(wb + 3 * S_)] = (f32x2){u3r * w3[0] - u3i * w3[1],              \
                                      u3r * w3[1] + u3i * w3[0]};             \
        __syncthreads();                                                      \
    }

    STAGE(4,  Y, X)    // stage 2
    STAGE(16, X, Y)    // stage 3
    STAGE(64, Y, X)    // stage 4
#undef STAGE

    // ---- phase 5: stage 5 (S=256, p=0, unit twiddles) fused with epilogue ----
    {
        f32x2 a = X[PD(tid)];
        f32x2 b = X[PD(tid + 256)];
        f32x2 c = X[PD(tid + 512)];
        f32x2 d = X[PD(tid + 768)];
        float apcr = a[0] + c[0], apci = a[1] + c[1];
        float amcr = a[0] - c[0], amci = a[1] - c[1];
        float bpdr = b[0] + d[0], bpdi = b[1] + d[1];
        float jbr  = -(b[1] - d[1]), jbi = (b[0] - d[0]);
        f32x2 y0 = (f32x2){apcr + bpdr, apci + bpdi};   // n = tid
        f32x2 y1 = (f32x2){amcr + jbr,  amci + jbi };   // n = tid+256
        f32x2 y2 = (f32x2){apcr - bpdr, apci - bpdi};   // n = tid+512
        f32x2 y3 = (f32x2){amcr - jbr,  amci - jbi };   // n = tid+768

        const float inv = 1.0f / 1024.0f;
        unsigned short* fR = frames + (size_t)r0 * 1024;
        unsigned short* fI = fR + 1024;
        float s0 = sqrtf(ola[tid])       * inv;
        float s1 = sqrtf(ola[tid + 256]) * inv;
        float s2 = sqrtf(ola[tid + 512]) * inv;
        float s3 = sqrtf(ola[tid + 768]) * inv;
        fR[tid]       = f2bf(y0[0] * s0);  fI[tid]       = f2bf(y0[1] * s0);
        fR[tid + 256] = f2bf(y1[0] * s1);  fI[tid + 256] = f2bf(y1[1] * s1);
        fR[tid + 512] = f2bf(y2[0] * s2);  fI[tid + 512] = f2bf(y2[1] * s2);
        fR[tid + 768] = f2bf(y3[0] * s3);  fI[tid + 768] = f2bf(y3[1] * s3);
    }
}

// ================= kernel 2: OLA gather, 4 samples/thread =================
__global__ __launch_bounds__(256) void ola_fold4(
    const unsigned short* __restrict__ frames, const float* __restrict__ ola,
    float* __restrict__ out) {
    const int col0 = (blockIdx.x * 256 + threadIdx.x) * 4;
    if (col0 >= OUTCOLS) return;
    const int b  = blockIdx.y;
    const int s  = col0 + 512;     // uncropped sample index
    const int g  = s >> 8;
    const int ls = s & 255;        // multiple of 4

    float a0 = 0.f, a1 = 0.f, a2 = 0.f, a3 = 0.f;
    float w0 = 0.f, w1 = 0.f, w2 = 0.f, w3 = 0.f;
#pragma unroll
    for (int j = 0; j < 4; ++j) {
        const int t = g - j;
        if (t >= 0 && t < NFRAMES) {
            uint2v u = *(const uint2v*)(frames + (((size_t)(b * NFRAMES + t)) << 10) + ls + 256 * j);
            a0 += __uint_as_float(u[0] << 16);
            a1 += __uint_as_float(u[0] & 0xffff0000u);
            a2 += __uint_as_float(u[1] << 16);
            a3 += __uint_as_float(u[1] & 0xffff0000u);
            f32x4 o = *(const f32x4*)(ola + ls + 256 * j);
            w0 += o[0]; w1 += o[1]; w2 += o[2]; w3 += o[3];
        }
    }
    f32x4 r = (f32x4){a0 / fmaxf(w0, 1e-11f), a1 / fmaxf(w1, 1e-11f),
                      a2 / fmaxf(w2, 1e-11f), a3 / fmaxf(w3, 1e-11f)};
    *(f32x4*)(out + (size_t)b * OUTCOLS + col0) = r;
}

// ================= last-resort naive fallback (round-1, proven) =================
__global__ __launch_bounds__(256) void istft_naive(
    const float* __restrict__ re, const float* __restrict__ im,
    const float* __restrict__ Wr, const float* __restrict__ Wi,
    const float* __restrict__ ola, float* __restrict__ out) {
    const int g = blockIdx.x + 2, b = blockIdx.y, ls = threadIdx.x;
    __shared__ float s_fr[4][FREQ];
    __shared__ float s_fi[4][FREQ];
#pragma unroll
    for (int jj = 0; jj < 4; ++jj) {
        const int t = g - jj;
        const bool valid = (t >= 0 && t < NFRAMES);
        const size_t base = ((size_t)b * NFRAMES + (valid ? t : 0)) * FREQ;
        for (int k = ls; k < FREQ; k += 256) {
            const float f = (k == 0 || k == FREQ - 1) ? 1.0f : 2.0f;
            s_fr[jj][k] = valid ? re[base + k] * f : 0.0f;
            s_fi[jj][k] = valid ? im[base + k] * f : 0.0f;
        }
    }
    __syncthreads();
    const float* wr = Wr + ls;
    const float* wi = Wi + ls;
    float acc = 0.0f;
    for (int k = 0; k < FREQ; ++k) {
        const float* wrk = wr + (size_t)k * 1024;
        const float* wik = wi + (size_t)k * 1024;
#pragma unroll
        for (int jj = 0; jj < 4; ++jj) {
            acc = fmaf(wrk[jj * 256], s_fr[jj][k], acc);
            acc = fmaf(-wik[jj * 256], s_fi[jj][k], acc);
        }
    }
    float wsv = 0.0f;
#pragma unroll
    for (int jj = 0; jj < 4; ++jj) {
        const int t = g - jj;
        if (t >= 0 && t < NFRAMES) wsv += ola[ls + jj * 256];
    }
    wsv = fmaxf(wsv, 1e-11f);
    out[(size_t)b * OUTCOLS + (g * 256 + ls - 512)] = acc / wsv;
}

extern "C" void kernel_launch(void* const* d_in, const int* in_sizes, int n_in,
                              void* d_out, int out_size, void* d_ws, size_t ws_size,
                              hipStream_t stream) {
    const float* re  = (const float*)d_in[0];
    const float* im  = (const float*)d_in[1];
    const float* Wr  = (const float*)d_in[2];
    const float* Wi  = (const float*)d_in[3];
    const float* ola = (const float*)d_in[4];
    float* out = (float*)d_out;

    if (ws_size >= WS_NEED) {
        unsigned short* frames = (unsigned short*)d_ws;
        float* tw = (float*)((char*)d_ws + TW_OFF);
        hipLaunchKernelGGL(twiddle_prep, dim3(4), dim3(256), 0, stream, tw);
        hipLaunchKernelGGL(ifft_frames5, dim3(8192), dim3(256), 0, stream,
                           re, im, ola, tw, frames);
        hipLaunchKernelGGL(ola_fold4, dim3(512, BATCH), dim3(256), 0, stream,
                           frames, ola, out);
    } else {
        dim3 grid(2047, BATCH);
        hipLaunchKernelGGL(istft_naive, grid, dim3(256), 0, stream,
                           re, im, Wr, Wi, ola, out);
    }
}

// Round 15
// 42.114 us; speedup vs baseline: 1.1121x; 1.0244x over previous
//
#include <hip/hip_runtime.h>

// ISTFT via FFT, two-frames-per-transform pack, 5-phase fused pipeline,
// PACKED-FP32 butterflies (v_pk_* via f32x2 vector arithmetic):
//   frames[b,t,n] = Re{ sum_k X_t[k] e^{+2pi i kn/1024} } * hann[n]/1024
// Pack Z[k] = X_{2m}[k] + i*X_{2m+1}[k] -> one 1024-pt complex inverse FFT gives
// frame 2m = Re z, frame 2m+1 = Im z. im[k=0]/im[k=512] ZEROED when packing.
// Twiddle table entries are (c, s, -s, c) so cmul = pk_mul + pk_fma:
//   u*(c+is) = u.x*(c,s) + u.y*(-s,c).
// Radix-4 DIF Stockham (proven r12/r14): stage S reads idx tid+256k, writes
// 4Sp+q+Sk, twiddles tw[pS],tw[2pS],tw[3pS]; +i convention; stage 1 fused with
// hermitian global loads, stage 5 (unit twiddles) fused with scale+store.
// LDS PD16 padding with closed-form padded indices (no per-access pad math):
//   reads:  rpd + 272k,           rpd  = tid + (tid>>4)
//   S=4  writes: 17p+q   + 4k     (p=tid>>2, q=tid&3)
//   S=16 writes: 68p+q   + 17k    (p=tid>>4, q=tid&15)
//   S=64 writes: 272p+q+(q>>4) + 68k  (p=tid>>6, q=tid&63)
//   S=1  writes: 4*tid+(tid>>2) + k

#define BATCH    8
#define NFRAMES  2048
#define FREQ     513
#define OUTCOLS  524032
#define FRAMES_B ((size_t)16384 * 1024 * 2)    // 32 MB bf16 frames
#define TW_OFF   FRAMES_B                      // f32x4 table, 16 KB
#define HANN_OFF (FRAMES_B + 16384)            // f32 table, 4 KB
#define WS_NEED  (FRAMES_B + 16384 + 4096)

typedef __attribute__((ext_vector_type(2))) float f32x2;
typedef __attribute__((ext_vector_type(4))) float f32x4;
typedef __attribute__((ext_vector_type(2))) unsigned uint2v;

__device__ __forceinline__ unsigned short f2bf(float x) {
    unsigned u = __float_as_uint(x);
    return (unsigned short)((u + 0x7fffu + ((u >> 16) & 1u)) >> 16);
}

// complex mul via packed ops: w4 = (c, s, -s, c); returns u * (c + i s)
__device__ __forceinline__ f32x2 cmul(f32x2 u, f32x4 w4) {
    return (f32x2){u[0], u[0]} * (f32x2){w4[0], w4[1]}
         + (f32x2){u[1], u[1]} * (f32x2){w4[2], w4[3]};
}

// ================= kernel 0: twiddle + hann tables =================
__global__ __launch_bounds__(256) void table_prep(const float* __restrict__ ola,
                                                  float* __restrict__ tw4,
                                                  float* __restrict__ hann) {
    int k = blockIdx.x * 256 + threadIdx.x;    // 0..1023
    float s, c;
    sincosf(6.283185307179586f * (float)k * (1.0f / 1024.0f), &s, &c);
    ((f32x4*)tw4)[k] = (f32x4){c, s, -s, c};
    hann[k] = sqrtf(ola[k]) * (1.0f / 1024.0f);
}

// ================= kernel 1: 1024-pt IFFT per frame-pair, 5-phase =================
__global__ __launch_bounds__(256) void ifft_frames6(
    const float* __restrict__ re, const float* __restrict__ im,
    const float* __restrict__ twg, const float* __restrict__ hann,
    unsigned short* __restrict__ frames) {
    __shared__ f32x2 X[1088], Y[1088];

    const int r0  = blockIdx.x * 2;
    const int tid = threadIdx.x;
    const f32x4* tw4 = (const f32x4*)twg;
    const int rpd = tid + (tid >> 4);          // padded read base

    const float* fre0 = re + (size_t)r0 * FREQ;
    const float* fim0 = im + (size_t)r0 * FREQ;
    const float* fre1 = fre0 + FREQ;
    const float* fim1 = fim0 + FREQ;

    // ---- phase 1: hermitian-packed loads + stage-1 butterfly (S=1), write Y ----
    {
        f32x2 a, b, c, d;
        {   // a: n = tid; DC (tid==0) imag-zeroed
            float A1 = fre0[tid], B1 = fim0[tid];
            float A2 = fre1[tid], B2 = fim1[tid];
            if (tid == 0) { B1 = 0.0f; B2 = 0.0f; }
            a = (f32x2){A1 - B2, B1 + A2};
        }
        {   // b: n = tid+256
            float A1 = fre0[tid + 256], B1 = fim0[tid + 256];
            float A2 = fre1[tid + 256], B2 = fim1[tid + 256];
            b = (f32x2){A1 - B2, B1 + A2};
        }
        {   // c: n = tid+512 -> mirror m = 512-tid; tid==0 = Nyquist, imag-zeroed
            int m = 512 - tid;
            float A1 = fre0[m], B1 = fim0[m];
            float A2 = fre1[m], B2 = fim1[m];
            if (tid == 0) { B1 = 0.0f; B2 = 0.0f; }
            c = (f32x2){A1 + B2, A2 - B1};
        }
        {   // d: n = tid+768 -> mirror m = 256-tid
            int m = 256 - tid;
            float A1 = fre0[m], B1 = fim0[m];
            float A2 = fre1[m], B2 = fim1[m];
            d = (f32x2){A1 + B2, A2 - B1};
        }
        f32x2 apc = a + c, amc = a - c, bpd = b + d, bmd = b - d;
        f32x2 jb = (f32x2){-bmd[1], bmd[0]};   // i*(b-d)
        f32x4 w1 = tw4[tid], w2 = tw4[2 * tid], w3 = tw4[3 * tid];
        const int wb = 4 * tid + (tid >> 2);   // PD(4*tid), offsets +1,+2,+3
        Y[wb]     = apc + bpd;
        Y[wb + 1] = cmul(amc + jb, w1);
        Y[wb + 2] = cmul(apc - bpd, w2);
        Y[wb + 3] = cmul(amc - jb, w3);
    }
    __syncthreads();

    // ---- phases 2-4: Stockham stages with closed-form padded indices ----
#define STAGE(S, P, Q, WBASE, O, RB, WB)                                      \
    {                                                                         \
        const int p  = (P);                                                   \
        const int t1 = p * (S);                                               \
        f32x4 w1 = tw4[t1], w2 = tw4[2 * t1], w3 = tw4[3 * t1];               \
        f32x2 a = RB[rpd],       b = RB[rpd + 272];                           \
        f32x2 c = RB[rpd + 544], d = RB[rpd + 816];                           \
        f32x2 apc = a + c, amc = a - c, bpd = b + d, bmd = b - d;             \
        f32x2 jb = (f32x2){-bmd[1], bmd[0]};                                  \
        const int wb = (WBASE);                                               \
        WB[wb]           = apc + bpd;                                         \
        WB[wb + (O)]     = cmul(amc + jb, w1);                                \
        WB[wb + 2 * (O)] = cmul(apc - bpd, w2);                               \
        WB[wb + 3 * (O)] = cmul(amc - jb, w3);                                \
        __syncthreads();                                                      \
    }

    STAGE(4,  tid >> 2, tid & 3,  17 * (tid >> 2) + (tid & 3),  4,  Y, X)
    STAGE(16, tid >> 4, tid & 15, 68 * (tid >> 4) + (tid & 15), 17, X, Y)
    STAGE(64, tid >> 6, tid & 63,
          272 * (tid >> 6) + (tid & 63) + ((tid & 63) >> 4),    68, Y, X)
#undef STAGE

    // ---- phase 5: stage 5 (S=256, p=0, unit twiddles) fused with epilogue ----
    {
        f32x2 a = X[rpd],       b = X[rpd + 272];
        f32x2 c = X[rpd + 544], d = X[rpd + 816];
        f32x2 apc = a + c, amc = a - c, bpd = b + d, bmd = b - d;
        f32x2 jb = (f32x2){-bmd[1], bmd[0]};
        f32x2 y0 = apc + bpd;    // n = tid
        f32x2 y1 = amc + jb;     // n = tid+256
        f32x2 y2 = apc - bpd;    // n = tid+512
        f32x2 y3 = amc - jb;     // n = tid+768

        unsigned short* fR = frames + (size_t)r0 * 1024;
        unsigned short* fI = fR + 1024;
        float s0 = hann[tid];
        float s1 = hann[tid + 256];
        float s2 = hann[tid + 512];
        float s3 = hann[tid + 768];
        fR[tid]       = f2bf(y0[0] * s0);  fI[tid]       = f2bf(y0[1] * s0);
        fR[tid + 256] = f2bf(y1[0] * s1);  fI[tid + 256] = f2bf(y1[1] * s1);
        fR[tid + 512] = f2bf(y2[0] * s2);  fI[tid + 512] = f2bf(y2[1] * s2);
        fR[tid + 768] = f2bf(y3[0] * s3);  fI[tid + 768] = f2bf(y3[1] * s3);
    }
}

// ================= kernel 2: OLA gather, 4 samples/thread =================
__global__ __launch_bounds__(256) void ola_fold4(
    const unsigned short* __restrict__ frames, const float* __restrict__ ola,
    float* __restrict__ out) {
    const int col0 = (blockIdx.x * 256 + threadIdx.x) * 4;
    if (col0 >= OUTCOLS) return;
    const int b  = blockIdx.y;
    const int s  = col0 + 512;     // uncropped sample index
    const int g  = s >> 8;
    const int ls = s & 255;        // multiple of 4

    float a0 = 0.f, a1 = 0.f, a2 = 0.f, a3 = 0.f;
    float w0 = 0.f, w1 = 0.f, w2 = 0.f, w3 = 0.f;
#pragma unroll
    for (int j = 0; j < 4; ++j) {
        const int t = g - j;
        if (t >= 0 && t < NFRAMES) {
            uint2v u = *(const uint2v*)(frames + (((size_t)(b * NFRAMES + t)) << 10) + ls + 256 * j);
            a0 += __uint_as_float(u[0] << 16);
            a1 += __uint_as_float(u[0] & 0xffff0000u);
            a2 += __uint_as_float(u[1] << 16);
            a3 += __uint_as_float(u[1] & 0xffff0000u);
            f32x4 o = *(const f32x4*)(ola + ls + 256 * j);
            w0 += o[0]; w1 += o[1]; w2 += o[2]; w3 += o[3];
        }
    }
    f32x4 r = (f32x4){a0 / fmaxf(w0, 1e-11f), a1 / fmaxf(w1, 1e-11f),
                      a2 / fmaxf(w2, 1e-11f), a3 / fmaxf(w3, 1e-11f)};
    *(f32x4*)(out + (size_t)b * OUTCOLS + col0) = r;
}

// ================= last-resort naive fallback (round-1, proven) =================
__global__ __launch_bounds__(256) void istft_naive(
    const float* __restrict__ re, const float* __restrict__ im,
    const float* __restrict__ Wr, const float* __restrict__ Wi,
    const float* __restrict__ ola, float* __restrict__ out) {
    const int g = blockIdx.x + 2, b = blockIdx.y, ls = threadIdx.x;
    __shared__ float s_fr[4][FREQ];
    __shared__ float s_fi[4][FREQ];
#pragma unroll
    for (int jj = 0; jj < 4; ++jj) {
        const int t = g - jj;
        const bool valid = (t >= 0 && t < NFRAMES);
        const size_t base = ((size_t)b * NFRAMES + (valid ? t : 0)) * FREQ;
        for (int k = ls; k < FREQ; k += 256) {
            const float f = (k == 0 || k == FREQ - 1) ? 1.0f : 2.0f;
            s_fr[jj][k] = valid ? re[base + k] * f : 0.0f;
            s_fi[jj][k] = valid ? im[base + k] * f : 0.0f;
        }
    }
    __syncthreads();
    const float* wr = Wr + ls;
    const float* wi = Wi + ls;
    float acc = 0.0f;
    for (int k = 0; k < FREQ; ++k) {
        const float* wrk = wr + (size_t)k * 1024;
        const float* wik = wi + (size_t)k * 1024;
#pragma unroll
        for (int jj = 0; jj < 4; ++jj) {
            acc = fmaf(wrk[jj * 256], s_fr[jj][k], acc);
            acc = fmaf(-wik[jj * 256], s_fi[jj][k], acc);
        }
    }
    float wsv = 0.0f;
#pragma unroll
    for (int jj = 0; jj < 4; ++jj) {
        const int t = g - jj;
        if (t >= 0 && t < NFRAMES) wsv += ola[ls + jj * 256];
    }
    wsv = fmaxf(wsv, 1e-11f);
    out[(size_t)b * OUTCOLS + (g * 256 + ls - 512)] = acc / wsv;
}

extern "C" void kernel_launch(void* const* d_in, const int* in_sizes, int n_in,
                              void* d_out, int out_size, void* d_ws, size_t ws_size,
                              hipStream_t stream) {
    const float* re  = (const float*)d_in[0];
    const float* im  = (const float*)d_in[1];
    const float* Wr  = (const float*)d_in[2];
    const float* Wi  = (const float*)d_in[3];
    const float* ola = (const float*)d_in[4];
    float* out = (float*)d_out;

    if (ws_size >= WS_NEED) {
        unsigned short* frames = (unsigned short*)d_ws;
        float* tw   = (float*)((char*)d_ws + TW_OFF);
        float* hann = (float*)((char*)d_ws + HANN_OFF);
        hipLaunchKernelGGL(table_prep, dim3(4), dim3(256), 0, stream, ola, tw, hann);
        hipLaunchKernelGGL(ifft_frames6, dim3(8192), dim3(256), 0, stream,
                           re, im, tw, hann, frames);
        hipLaunchKernelGGL(ola_fold4, dim3(512, BATCH), dim3(256), 0, stream,
                           frames, ola, out);
    } else {
        dim3 grid(2047, BATCH);
        hipLaunchKernelGGL(istft_naive, grid, dim3(256), 0, stream,
                           re, im, Wr, Wi, ola, out);
    }
}

// Round 16
// 42.063 us; speedup vs baseline: 1.1135x; 1.0012x over previous
//
#include <hip/hip_runtime.h>

// ISTFT via FFT, two-frames-per-transform pack, WAVE-LOCAL FFT:
// one 1024-pt inverse FFT per 64-lane wave, 16 points/lane, radix-4 DIF
// Stockham with stage pairs fused in registers:
//   stage1+2 in regs -> LDS exchange -> stage3+4 in regs -> LDS exchange ->
//   stage5 (unit twiddles) + hann scale + bf16 store.
// Lane l owns: stage1 virtual threads {l+64j} (inputs Z[l+64j+256k]);
//   stage2 vthreads {4l+r} (inputs = stage1 outputs, in-lane j<->k transpose);
//   stage3 vthreads {l+64j}; stage4 vthreads {64(l>>4)+(l&15)+16r} (in-lane).
// Stockham rule (proven r12-r15): stage S reads n=t+256k, writes 4Sp+q+Sk,
// twiddles tw[pS],tw[2pS],tw[3pS], +i convention. LDS slot for natural n is
// n + (n>>4). Arithmetic is bit-identical to the r14/r15 passing kernels.
// Pack Z[k]=X1[k]+i*X2[k]; im at DC/Nyquist ZEROED (round-9 lesson).
// Twiddle table entries (c,s,-s,c): cmul = 2 packed ops.

#define BATCH    8
#define NFRAMES  2048
#define FREQ     513
#define OUTCOLS  524032
#define FRAMES_B ((size_t)16384 * 1024 * 2)    // 32 MB bf16 frames
#define TW_OFF   FRAMES_B                      // f32x4 table, 16 KB
#define HANN_OFF (FRAMES_B + 16384)            // f32 table, 4 KB
#define WS_NEED  (FRAMES_B + 16384 + 4096)

typedef __attribute__((ext_vector_type(2))) float f32x2;
typedef __attribute__((ext_vector_type(4))) float f32x4;
typedef __attribute__((ext_vector_type(2))) unsigned uint2v;

__device__ __forceinline__ unsigned short f2bf(float x) {
    unsigned u = __float_as_uint(x);
    return (unsigned short)((u + 0x7fffu + ((u >> 16) & 1u)) >> 16);
}

// complex mul via packed ops: w4 = (c, s, -s, c); returns u * (c + i s)
__device__ __forceinline__ f32x2 cmul(f32x2 u, f32x4 w4) {
    return (f32x2){u[0], u[0]} * (f32x2){w4[0], w4[1]}
         + (f32x2){u[1], u[1]} * (f32x2){w4[2], w4[3]};
}

// ================= kernel 0: twiddle + hann tables =================
__global__ __launch_bounds__(256) void table_prep(const float* __restrict__ ola,
                                                  float* __restrict__ tw4,
                                                  float* __restrict__ hann) {
    int k = blockIdx.x * 256 + threadIdx.x;    // 0..1023
    float s, c;
    sincosf(6.283185307179586f * (float)k * (1.0f / 1024.0f), &s, &c);
    ((f32x4*)tw4)[k] = (f32x4){c, s, -s, c};
    hann[k] = sqrtf(ola[k]) * (1.0f / 1024.0f);
}

// ================= kernel 1: wave-local 1024-pt IFFT per frame-pair =================
__global__ __launch_bounds__(64, 4) void ifft_wave(
    const float* __restrict__ re, const float* __restrict__ im,
    const float* __restrict__ twg, const float* __restrict__ hann,
    unsigned short* __restrict__ frames) {
    __shared__ f32x2 L[1088];                  // 1024 + PD16 padding, 8.7 KB

    const int l  = threadIdx.x;                // lane 0..63
    const int r0 = blockIdx.x * 2;
    const f32x4* tw4 = (const f32x4*)twg;

    const float* fre0 = re + (size_t)r0 * FREQ;
    const float* fim0 = im + (size_t)r0 * FREQ;
    const float* fre1 = fre0 + FREQ;
    const float* fim1 = fim0 + FREQ;

#define BFLY(IA, IB, IC, ID, T1, O0, O1, O2, O3)                              \
    {                                                                         \
        f32x2 apc = (IA) + (IC), amc = (IA) - (IC);                           \
        f32x2 bpd = (IB) + (ID), bmd = (IB) - (ID);                           \
        f32x2 jb  = (f32x2){-bmd[1], bmd[0]};   /* i*(b-d) */                 \
        O0 = apc + bpd;                                                       \
        O1 = cmul(amc + jb, w1##T1);                                          \
        O2 = cmul(apc - bpd, w2##T1);                                         \
        O3 = cmul(amc - jb, w3##T1);                                          \
    }

    // ---- stage 1 (S=1, vthreads l+64j): hermitian-packed global loads ----
    f32x2 s1[4][4];
#pragma unroll
    for (int j = 0; j < 4; ++j) {
        f32x2 in[4];
#pragma unroll
        for (int k = 0; k < 4; ++k) {
            int n  = l + 64 * j + 256 * k;
            int mm = (n <= 512) ? n : (1024 - n);
            float A1 = fre0[mm], B1 = fim0[mm];
            float A2 = fre1[mm], B2 = fim1[mm];
            if (n == 0 || n == 512) { B1 = 0.0f; B2 = 0.0f; }  // DC/Nyq imag->0
            in[k] = (n <= 512) ? (f32x2){A1 - B2, B1 + A2}
                               : (f32x2){A1 + B2, A2 - B1};
        }
        const int t1 = l + 64 * j;
        f32x4 w1A = tw4[t1], w2A = tw4[2 * t1], w3A = tw4[3 * t1];
        BFLY(in[0], in[1], in[2], in[3], A, s1[j][0], s1[j][1], s1[j][2], s1[j][3]);
    }

    // ---- stage 2 (S=4, vthreads 4l+r, in-lane): outputs n = 16l + 4k + r ----
    {
        const int t1 = 4 * l;
        f32x4 w1B = tw4[t1], w2B = tw4[2 * t1], w3B = tw4[3 * t1];
#pragma unroll
        for (int r = 0; r < 4; ++r) {
            f32x2 o0, o1, o2, o3;
            BFLY(s1[0][r], s1[1][r], s1[2][r], s1[3][r], B, o0, o1, o2, o3);
            int n0 = 16 * l + r;
            L[n0      + (n0 >> 4)]        = o0;
            L[n0 + 4  + ((n0 + 4) >> 4)]  = o1;
            L[n0 + 8  + ((n0 + 8) >> 4)]  = o2;
            L[n0 + 12 + ((n0 + 12) >> 4)] = o3;
        }
    }
    __syncthreads();

    // ---- stage 3 (S=16, vthreads l+64j): read exchange 1 ----
    f32x2 s3[4][4];
#pragma unroll
    for (int j = 0; j < 4; ++j) {
        f32x2 in[4];
#pragma unroll
        for (int k = 0; k < 4; ++k) {
            int n = l + 64 * j + 256 * k;
            in[k] = L[n + (n >> 4)];
        }
        const int t1 = ((l + 64 * j) >> 4) << 4;
        f32x4 w1C = tw4[t1], w2C = tw4[2 * t1], w3C = tw4[3 * t1];
        BFLY(in[0], in[1], in[2], in[3], C, s3[j][0], s3[j][1], s3[j][2], s3[j][3]);
    }
    __syncthreads();   // all exchange-1 reads retired before overwrite

    // ---- stage 4 (S=64, in-lane): outputs n = 256(l>>4)+(l&15)+16r+64k ----
    {
        const int t1 = (l >> 4) << 6;
        f32x4 w1D = tw4[t1], w2D = tw4[2 * t1], w3D = tw4[3 * t1];
#pragma unroll
        for (int r = 0; r < 4; ++r) {
            f32x2 o0, o1, o2, o3;
            BFLY(s3[0][r], s3[1][r], s3[2][r], s3[3][r], D, o0, o1, o2, o3);
            int n0 = 256 * (l >> 4) + 16 * r + (l & 15);
            int n1 = n0 + 64, n2 = n0 + 128, n3 = n0 + 192;
            L[n0 + (n0 >> 4)] = o0;
            L[n1 + (n1 >> 4)] = o1;
            L[n2 + (n2 >> 4)] = o2;
            L[n3 + (n3 >> 4)] = o3;
        }
    }
    __syncthreads();

    // ---- stage 5 (S=256, unit twiddles) + hann + bf16 store ----
    unsigned short* fR = frames + (size_t)r0 * 1024;
    unsigned short* fI = fR + 1024;
#pragma unroll
    for (int h = 0; h < 4; ++h) {
        int n0 = l + 64 * h;
        int n1 = n0 + 256, n2 = n0 + 512, n3 = n0 + 768;
        f32x2 a = L[n0 + (n0 >> 4)];
        f32x2 b = L[n1 + (n1 >> 4)];
        f32x2 c = L[n2 + (n2 >> 4)];
        f32x2 d = L[n3 + (n3 >> 4)];
        f32x2 apc = a + c, amc = a - c, bpd = b + d, bmd = b - d;
        f32x2 jb  = (f32x2){-bmd[1], bmd[0]};
        f32x2 y0 = apc + bpd, y1 = amc + jb, y2 = apc - bpd, y3 = amc - jb;
        float h0 = hann[n0], h1 = hann[n1], h2 = hann[n2], h3 = hann[n3];
        fR[n0] = f2bf(y0[0] * h0);  fI[n0] = f2bf(y0[1] * h0);
        fR[n1] = f2bf(y1[0] * h1);  fI[n1] = f2bf(y1[1] * h1);
        fR[n2] = f2bf(y2[0] * h2);  fI[n2] = f2bf(y2[1] * h2);
        fR[n3] = f2bf(y3[0] * h3);  fI[n3] = f2bf(y3[1] * h3);
    }
#undef BFLY
}

// ================= kernel 2: OLA gather, 4 samples/thread =================
__global__ __launch_bounds__(256) void ola_fold4(
    const unsigned short* __restrict__ frames, const float* __restrict__ ola,
    float* __restrict__ out) {
    const int col0 = (blockIdx.x * 256 + threadIdx.x) * 4;
    if (col0 >= OUTCOLS) return;
    const int b  = blockIdx.y;
    const int s  = col0 + 512;     // uncropped sample index
    const int g  = s >> 8;
    const int ls = s & 255;        // multiple of 4

    float a0 = 0.f, a1 = 0.f, a2 = 0.f, a3 = 0.f;
    float w0 = 0.f, w1 = 0.f, w2 = 0.f, w3 = 0.f;
#pragma unroll
    for (int j = 0; j < 4; ++j) {
        const int t = g - j;
        if (t >= 0 && t < NFRAMES) {
            uint2v u = *(const uint2v*)(frames + (((size_t)(b * NFRAMES + t)) << 10) + ls + 256 * j);
            a0 += __uint_as_float(u[0] << 16);
            a1 += __uint_as_float(u[0] & 0xffff0000u);
            a2 += __uint_as_float(u[1] << 16);
            a3 += __uint_as_float(u[1] & 0xffff0000u);
            f32x4 o = *(const f32x4*)(ola + ls + 256 * j);
            w0 += o[0]; w1 += o[1]; w2 += o[2]; w3 += o[3];
        }
    }
    f32x4 r = (f32x4){a0 / fmaxf(w0, 1e-11f), a1 / fmaxf(w1, 1e-11f),
                      a2 / fmaxf(w2, 1e-11f), a3 / fmaxf(w3, 1e-11f)};
    *(f32x4*)(out + (size_t)b * OUTCOLS + col0) = r;
}

// ================= last-resort naive fallback (round-1, proven) =================
__global__ __launch_bounds__(256) void istft_naive(
    const float* __restrict__ re, const float* __restrict__ im,
    const float* __restrict__ Wr, const float* __restrict__ Wi,
    const float* __restrict__ ola, float* __restrict__ out) {
    const int g = blockIdx.x + 2, b = blockIdx.y, ls = threadIdx.x;
    __shared__ float s_fr[4][FREQ];
    __shared__ float s_fi[4][FREQ];
#pragma unroll
    for (int jj = 0; jj < 4; ++jj) {
        const int t = g - jj;
        const bool valid = (t >= 0 && t < NFRAMES);
        const size_t base = ((size_t)b * NFRAMES + (valid ? t : 0)) * FREQ;
        for (int k = ls; k < FREQ; k += 256) {
            const float f = (k == 0 || k == FREQ - 1) ? 1.0f : 2.0f;
            s_fr[jj][k] = valid ? re[base + k] * f : 0.0f;
            s_fi[jj][k] = valid ? im[base + k] * f : 0.0f;
        }
    }
    __syncthreads();
    const float* wr = Wr + ls;
    const float* wi = Wi + ls;
    float acc = 0.0f;
    for (int k = 0; k < FREQ; ++k) {
        const float* wrk = wr + (size_t)k * 1024;
        const float* wik = wi + (size_t)k * 1024;
#pragma unroll
        for (int jj = 0; jj < 4; ++jj) {
            acc = fmaf(wrk[jj * 256], s_fr[jj][k], acc);
            acc = fmaf(-wik[jj * 256], s_fi[jj][k], acc);
        }
    }
    float wsv = 0.0f;
#pragma unroll
    for (int jj = 0; jj < 4; ++jj) {
        const int t = g - jj;
        if (t >= 0 && t < NFRAMES) wsv += ola[ls + jj * 256];
    }
    wsv = fmaxf(wsv, 1e-11f);
    out[(size_t)b * OUTCOLS + (g * 256 + ls - 512)] = acc / wsv;
}

extern "C" void kernel_launch(void* const* d_in, const int* in_sizes, int n_in,
                              void* d_out, int out_size, void* d_ws, size_t ws_size,
                              hipStream_t stream) {
    const float* re  = (const float*)d_in[0];
    const float* im  = (const float*)d_in[1];
    const float* Wr  = (const float*)d_in[2];
    const float* Wi  = (const float*)d_in[3];
    const float* ola = (const float*)d_in[4];
    float* out = (float*)d_out;

    if (ws_size >= WS_NEED) {
        unsigned short* frames = (unsigned short*)d_ws;
        float* tw   = (float*)((char*)d_ws + TW_OFF);
        float* hann = (float*)((char*)d_ws + HANN_OFF);
        hipLaunchKernelGGL(table_prep, dim3(4), dim3(256), 0, stream, ola, tw, hann);
        hipLaunchKernelGGL(ifft_wave, dim3(8192), dim3(64), 0, stream,
                           re, im, tw, hann, frames);
        hipLaunchKernelGGL(ola_fold4, dim3(512, BATCH), dim3(256), 0, stream,
                           frames, ola, out);
    } else {
        dim3 grid(2047, BATCH);
        hipLaunchKernelGGL(istft_naive, grid, dim3(256), 0, stream,
                           re, im, Wr, Wi, ola, out);
    }
}

// Round 17
// 37.481 us; speedup vs baseline: 1.2496x; 1.1222x over previous
//
#include <hip/hip_runtime.h>

// ISTFT via FFT. Two-frames-per-FFT pack, WAVE-LOCAL 1024-pt radix-4 Stockham,
// 4 independent wave-FFTs per 256-thread block, ZERO barriers (per-wave LDS
// slice + in-order DS + lgkmcnt), twiddles computed on the fly (__sincosf +
// angle chain — no table, no gathers), plane-split LDS exchanges (Re then Im
// through one reused 4.2KB buffer) with +8*(n>>8) anti-conflict slot swizzle.
//   frames[b,t,n] = Re{ sum_k X_t[k] e^{+2pi i kn/1024} } * hann[n]/1024
// Pack Z[k]=X1[k]+i*X2[k] -> frame 2m = Re z, 2m+1 = Im z; im at DC/Nyquist
// ZEROED (round-9 lesson). Stockham rule (proven r12-r16): stage S reads
// n=t+256k, writes 4Sp+q+Sk, twiddles tw[pS],tw[2pS],tw[3pS], +i convention.
// Lane l owns: st1 vthreads {l+64j}; st2 {4l+r} (in-lane); st3 {l+64j};
// st4 {64(l>>4)+(l&15)+16r} (in-lane); st5 unit-twiddle + hann + bf16 store.
// Exchange slot for natural n: n + 8*(n>>8)  (verified conflict-free).

#define BATCH    8
#define NFRAMES  2048
#define FREQ     513
#define OUTCOLS  524032
#define FRAMES_B ((size_t)16384 * 1024 * 2)    // 32 MB bf16 frames
#define WS_NEED  FRAMES_B

typedef __attribute__((ext_vector_type(2))) float f32x2;
typedef __attribute__((ext_vector_type(4))) float f32x4;
typedef __attribute__((ext_vector_type(2))) unsigned uint2v;

__device__ __forceinline__ unsigned short f2bf(float x) {
    unsigned u = __float_as_uint(x);
    return (unsigned short)((u + 0x7fffu + ((u >> 16) & 1u)) >> 16);
}

#define DSYNC() do { asm volatile("s_waitcnt lgkmcnt(0)" ::: "memory"); \
                     __builtin_amdgcn_sched_barrier(0); } while (0)

// Butterfly with on-the-fly twiddles for base index T1 (angle 2pi*T1/1024).
// w2/w3 by double/triple-angle chain; compiler CSEs repeated same-T1 calls.
#define BFLY(IA, IB, IC, ID, T1, O0, O1, O2, O3)                              \
    {                                                                         \
        f32x2 apc = (IA) + (IC), amc = (IA) - (IC);                           \
        f32x2 bpd = (IB) + (ID), bmd = (IB) - (ID);                           \
        f32x2 jb  = (f32x2){-bmd[1], bmd[0]};   /* i*(b-d) */                 \
        float s1_, c1_;                                                       \
        __sincosf((float)(T1) * 6.135923151542565e-3f, &s1_, &c1_);           \
        float c2_ = fmaf(-2.0f * s1_, s1_, 1.0f), s2_ = 2.0f * s1_ * c1_;     \
        float c3_ = c2_ * c1_ - s2_ * s1_, s3_ = s2_ * c1_ + c2_ * s1_;       \
        f32x2 u1 = amc + jb, u2 = apc - bpd, u3 = amc - jb;                   \
        O0 = apc + bpd;                                                       \
        O1 = (f32x2){u1[0] * c1_ - u1[1] * s1_, u1[0] * s1_ + u1[1] * c1_};   \
        O2 = (f32x2){u2[0] * c2_ - u2[1] * s2_, u2[0] * s2_ + u2[1] * c2_};   \
        O3 = (f32x2){u3[0] * c3_ - u3[1] * s3_, u3[0] * s3_ + u3[1] * c3_};   \
    }

// ================= kernel 1: 4 wave-local IFFTs per block =================
__global__ __launch_bounds__(256, 5) void ifft_wave4(
    const float* __restrict__ re, const float* __restrict__ im,
    const float* __restrict__ ola, unsigned short* __restrict__ frames) {
    __shared__ float L[4][1052];               // one 4.2KB plane buffer per wave

    const int tid = threadIdx.x;
    const int l   = tid & 63;
    const int w   = tid >> 6;
    const int r0  = (blockIdx.x * 4 + w) * 2;  // this wave's frame pair
    float* P = &L[w][0];

    const float* fre0 = re + (size_t)r0 * FREQ;
    const float* fim0 = im + (size_t)r0 * FREQ;
    const float* fre1 = fre0 + FREQ;
    const float* fim1 = fim0 + FREQ;

    // ---- stage 1 (S=1, vthreads l+64j): hermitian-packed global loads ----
    f32x2 s1v[4][4];
#pragma unroll
    for (int j = 0; j < 4; ++j) {
        f32x2 in[4];
#pragma unroll
        for (int k = 0; k < 4; ++k) {
            int n  = l + 64 * j + 256 * k;
            int mm = (n <= 512) ? n : (1024 - n);
            float A1 = fre0[mm], B1 = fim0[mm];
            float A2 = fre1[mm], B2 = fim1[mm];
            if (n == 0 || n == 512) { B1 = 0.0f; B2 = 0.0f; }  // DC/Nyq imag->0
            in[k] = (n <= 512) ? (f32x2){A1 - B2, B1 + A2}
                               : (f32x2){A1 + B2, A2 - B1};
        }
        BFLY(in[0], in[1], in[2], in[3], l + 64 * j,
             s1v[j][0], s1v[j][1], s1v[j][2], s1v[j][3]);
    }

    // ---- stage 2 (S=4, vthreads 4l+r, in-lane): out n = 16l + 4k + r ----
    f32x4 wRe[4], wIm[4];
#pragma unroll
    for (int r = 0; r < 4; ++r) {
        f32x2 o0, o1, o2, o3;
        BFLY(s1v[0][r], s1v[1][r], s1v[2][r], s1v[3][r], 4 * l, o0, o1, o2, o3);
        wRe[0][r] = o0[0]; wIm[0][r] = o0[1];
        wRe[1][r] = o1[0]; wIm[1][r] = o1[1];
        wRe[2][r] = o2[0]; wIm[2][r] = o2[1];
        wRe[3][r] = o3[0]; wIm[3][r] = o3[1];
    }

    // ---- exchange 1, Re plane: write b128 (slot 16l+4k+8*(l>>4)), read b32 ----
    {
        const int wb = 16 * l + 8 * (l >> 4);
#pragma unroll
        for (int k = 0; k < 4; ++k) *(f32x4*)&P[wb + 4 * k] = wRe[k];
    }
    DSYNC();
    float rr[4][4], ri[4][4];
#pragma unroll
    for (int j = 0; j < 4; ++j)
#pragma unroll
        for (int k = 0; k < 4; ++k) rr[j][k] = P[l + 64 * j + 264 * k];
    DSYNC();   // Re reads retired before Im overwrites (WAR)
    {
        const int wb = 16 * l + 8 * (l >> 4);
#pragma unroll
        for (int k = 0; k < 4; ++k) *(f32x4*)&P[wb + 4 * k] = wIm[k];
    }
    DSYNC();
#pragma unroll
    for (int j = 0; j < 4; ++j)
#pragma unroll
        for (int k = 0; k < 4; ++k) ri[j][k] = P[l + 64 * j + 264 * k];
    DSYNC();   // Im reads retired before exchange-2 overwrites

    // ---- stage 3 (S=16, vthreads l+64j) ----
    f32x2 s3v[4][4];
#pragma unroll
    for (int j = 0; j < 4; ++j) {
        f32x2 a = (f32x2){rr[j][0], ri[j][0]};
        f32x2 b = (f32x2){rr[j][1], ri[j][1]};
        f32x2 c = (f32x2){rr[j][2], ri[j][2]};
        f32x2 d = (f32x2){rr[j][3], ri[j][3]};
        BFLY(a, b, c, d, (((l + 64 * j) >> 4) << 4),
             s3v[j][0], s3v[j][1], s3v[j][2], s3v[j][3]);
    }

    // ---- stage 4 (S=64, in-lane): out n = 256(l>>4)+(l&15)+16r+64k ----
    float eRe[4][4], eIm[4][4];   // [k][r]
#pragma unroll
    for (int r = 0; r < 4; ++r) {
        f32x2 o0, o1, o2, o3;
        BFLY(s3v[0][r], s3v[1][r], s3v[2][r], s3v[3][r], ((l >> 4) << 6),
             o0, o1, o2, o3);
        eRe[0][r] = o0[0]; eIm[0][r] = o0[1];
        eRe[1][r] = o1[0]; eIm[1][r] = o1[1];
        eRe[2][r] = o2[0]; eIm[2][r] = o2[1];
        eRe[3][r] = o3[0]; eIm[3][r] = o3[1];
    }

    // ---- exchange 2, Re plane: write b32 (slot n+8*(l>>4)), read b32 ----
    {
        const int wb = 256 * (l >> 4) + (l & 15) + 8 * (l >> 4);
#pragma unroll
        for (int k = 0; k < 4; ++k)
#pragma unroll
            for (int r = 0; r < 4; ++r) P[wb + 16 * r + 64 * k] = eRe[k][r];
    }
    DSYNC();
    float yR[4][4], yI[4][4];     // [h][k]
#pragma unroll
    for (int h = 0; h < 4; ++h)
#pragma unroll
        for (int k = 0; k < 4; ++k) yR[h][k] = P[l + 64 * h + 264 * k];
    DSYNC();
    {
        const int wb = 256 * (l >> 4) + (l & 15) + 8 * (l >> 4);
#pragma unroll
        for (int k = 0; k < 4; ++k)
#pragma unroll
            for (int r = 0; r < 4; ++r) P[wb + 16 * r + 64 * k] = eIm[k][r];
    }
    DSYNC();
#pragma unroll
    for (int h = 0; h < 4; ++h)
#pragma unroll
        for (int k = 0; k < 4; ++k) yI[h][k] = P[l + 64 * h + 264 * k];
    DSYNC();

    // ---- stage 5 (S=256, unit twiddles) + hann + bf16 store ----
    unsigned short* fR = frames + (size_t)r0 * 1024;
    unsigned short* fI = fR + 1024;
#pragma unroll
    for (int h = 0; h < 4; ++h) {
        f32x2 a = (f32x2){yR[h][0], yI[h][0]};
        f32x2 b = (f32x2){yR[h][1], yI[h][1]};
        f32x2 c = (f32x2){yR[h][2], yI[h][2]};
        f32x2 d = (f32x2){yR[h][3], yI[h][3]};
        f32x2 apc = a + c, amc = a - c, bpd = b + d, bmd = b - d;
        f32x2 jb  = (f32x2){-bmd[1], bmd[0]};
        f32x2 y0 = apc + bpd, y1 = amc + jb, y2 = apc - bpd, y3 = amc - jb;
        int n0 = l + 64 * h;
        float h0 = sqrtf(ola[n0])       * (1.0f / 1024.0f);
        float h1 = sqrtf(ola[n0 + 256]) * (1.0f / 1024.0f);
        float h2 = sqrtf(ola[n0 + 512]) * (1.0f / 1024.0f);
        float h3 = sqrtf(ola[n0 + 768]) * (1.0f / 1024.0f);
        fR[n0]       = f2bf(y0[0] * h0);  fI[n0]       = f2bf(y0[1] * h0);
        fR[n0 + 256] = f2bf(y1[0] * h1);  fI[n0 + 256] = f2bf(y1[1] * h1);
        fR[n0 + 512] = f2bf(y2[0] * h2);  fI[n0 + 512] = f2bf(y2[1] * h2);
        fR[n0 + 768] = f2bf(y3[0] * h3);  fI[n0 + 768] = f2bf(y3[1] * h3);
    }
}

// ================= kernel 2: OLA gather, 4 samples/thread =================
__global__ __launch_bounds__(256) void ola_fold4(
    const unsigned short* __restrict__ frames, const float* __restrict__ ola,
    float* __restrict__ out) {
    const int col0 = (blockIdx.x * 256 + threadIdx.x) * 4;
    if (col0 >= OUTCOLS) return;
    const int b  = blockIdx.y;
    const int s  = col0 + 512;     // uncropped sample index
    const int g  = s >> 8;
    const int ls = s & 255;        // multiple of 4

    float a0 = 0.f, a1 = 0.f, a2 = 0.f, a3 = 0.f;
    float w0 = 0.f, w1 = 0.f, w2 = 0.f, w3 = 0.f;
#pragma unroll
    for (int j = 0; j < 4; ++j) {
        const int t = g - j;
        if (t >= 0 && t < NFRAMES) {
            uint2v u = *(const uint2v*)(frames + (((size_t)(b * NFRAMES + t)) << 10) + ls + 256 * j);
            a0 += __uint_as_float(u[0] << 16);
            a1 += __uint_as_float(u[0] & 0xffff0000u);
            a2 += __uint_as_float(u[1] << 16);
            a3 += __uint_as_float(u[1] & 0xffff0000u);
            f32x4 o = *(const f32x4*)(ola + ls + 256 * j);
            w0 += o[0]; w1 += o[1]; w2 += o[2]; w3 += o[3];
        }
    }
    f32x4 r = (f32x4){a0 / fmaxf(w0, 1e-11f), a1 / fmaxf(w1, 1e-11f),
                      a2 / fmaxf(w2, 1e-11f), a3 / fmaxf(w3, 1e-11f)};
    *(f32x4*)(out + (size_t)b * OUTCOLS + col0) = r;
}

// ================= last-resort naive fallback (round-1, proven) =================
__global__ __launch_bounds__(256) void istft_naive(
    const float* __restrict__ re, const float* __restrict__ im,
    const float* __restrict__ Wr, const float* __restrict__ Wi,
    const float* __restrict__ ola, float* __restrict__ out) {
    const int g = blockIdx.x + 2, b = blockIdx.y, ls = threadIdx.x;
    __shared__ float s_fr[4][FREQ];
    __shared__ float s_fi[4][FREQ];
#pragma unroll
    for (int jj = 0; jj < 4; ++jj) {
        const int t = g - jj;
        const bool valid = (t >= 0 && t < NFRAMES);
        const size_t base = ((size_t)b * NFRAMES + (valid ? t : 0)) * FREQ;
        for (int k = ls; k < FREQ; k += 256) {
            const float f = (k == 0 || k == FREQ - 1) ? 1.0f : 2.0f;
            s_fr[jj][k] = valid ? re[base + k] * f : 0.0f;
            s_fi[jj][k] = valid ? im[base + k] * f : 0.0f;
        }
    }
    __syncthreads();
    const float* wr = Wr + ls;
    const float* wi = Wi + ls;
    float acc = 0.0f;
    for (int k = 0; k < FREQ; ++k) {
        const float* wrk = wr + (size_t)k * 1024;
        const float* wik = wi + (size_t)k * 1024;
#pragma unroll
        for (int jj = 0; jj < 4; ++jj) {
            acc = fmaf(wrk[jj * 256], s_fr[jj][k], acc);
            acc = fmaf(-wik[jj * 256], s_fi[jj][k], acc);
        }
    }
    float wsv = 0.0f;
#pragma unroll
    for (int jj = 0; jj < 4; ++jj) {
        const int t = g - jj;
        if (t >= 0 && t < NFRAMES) wsv += ola[ls + jj * 256];
    }
    wsv = fmaxf(wsv, 1e-11f);
    out[(size_t)b * OUTCOLS + (g * 256 + ls - 512)] = acc / wsv;
}

extern "C" void kernel_launch(void* const* d_in, const int* in_sizes, int n_in,
                              void* d_out, int out_size, void* d_ws, size_t ws_size,
                              hipStream_t stream) {
    const float* re  = (const float*)d_in[0];
    const float* im  = (const float*)d_in[1];
    const float* Wr  = (const float*)d_in[2];
    const float* Wi  = (const float*)d_in[3];
    const float* ola = (const float*)d_in[4];
    float* out = (float*)d_out;

    if (ws_size >= WS_NEED) {
        unsigned short* frames = (unsigned short*)d_ws;
        hipLaunchKernelGGL(ifft_wave4, dim3(2048), dim3(256), 0, stream,
                           re, im, ola, frames);
        hipLaunchKernelGGL(ola_fold4, dim3(512, BATCH), dim3(256), 0, stream,
                           frames, ola, out);
    } else {
        dim3 grid(2047, BATCH);
        hipLaunchKernelGGL(istft_naive, grid, dim3(256), 0, stream,
                           re, im, Wr, Wi, ola, out);
    }
}

// Round 18
// 37.214 us; speedup vs baseline: 1.2586x; 1.0072x over previous
//
#include <hip/hip_runtime.h>

// ISTFT via FFT. Two-frames-per-FFT pack, WAVE-LOCAL 1024-pt radix-4 Stockham,
// 4 independent wave-FFTs per 256-thread block, ZERO barriers (per-wave LDS
// slice + in-order DS + lgkmcnt), twiddles via RAW v_sin/v_cos (input in
// revolutions: rev = T1/1024 exactly — no range reduction, no libm), plane-
// split LDS exchanges (Re then Im through one reused 4.2KB buffer/wave).
// Round 18: __launch_bounds__(256,2) — r16/r17 demanded occupancy (cap ~102
// VGPR) on a kernel with ~100-VGPR peak state -> suspected scratch spills
// (VGPR_Count=48 reported for 32 VGPRs of pure data). Let regalloc breathe.
//   frames[b,t,n] = Re{ sum_k X_t[k] e^{+2pi i kn/1024} } * hann[n]/1024
// Pack Z[k]=X1[k]+i*X2[k] -> frame 2m = Re z, 2m+1 = Im z; im at DC/Nyquist
// ZEROED (round-9 lesson). Stockham rule (proven r12-r17): stage S reads
// n=t+256k, writes 4Sp+q+Sk, twiddles tw[pS],tw[2pS],tw[3pS], +i convention.
// Lane l owns: st1 vthreads {l+64j}; st2 {4l+r} (in-lane); st3 {l+64j};
// st4 {64(l>>4)+(l&15)+16r} (in-lane); st5 unit-twiddle + hann + bf16 store.
// Exchange slot for natural n: n + 8*(n>>8)  (conflict-free, proven r17).

#define BATCH    8
#define NFRAMES  2048
#define FREQ     513
#define OUTCOLS  524032
#define FRAMES_B ((size_t)16384 * 1024 * 2)    // 32 MB bf16 frames
#define WS_NEED  FRAMES_B

typedef __attribute__((ext_vector_type(2))) float f32x2;
typedef __attribute__((ext_vector_type(4))) float f32x4;
typedef __attribute__((ext_vector_type(2))) unsigned uint2v;

__device__ __forceinline__ unsigned short f2bf(float x) {
    unsigned u = __float_as_uint(x);
    return (unsigned short)((u + 0x7fffu + ((u >> 16) & 1u)) >> 16);
}

#define DSYNC() do { asm volatile("s_waitcnt lgkmcnt(0)" ::: "memory"); \
                     __builtin_amdgcn_sched_barrier(0); } while (0)

// Butterfly; twiddle base T1 (angle 2pi*T1/1024). v_sin/v_cos take REVOLUTIONS:
// rev = T1/1024 in [0, 0.25]. w2/w3 by double/triple-angle chain.
#define BFLY(IA, IB, IC, ID, T1, O0, O1, O2, O3)                              \
    {                                                                         \
        f32x2 apc = (IA) + (IC), amc = (IA) - (IC);                           \
        f32x2 bpd = (IB) + (ID), bmd = (IB) - (ID);                           \
        f32x2 jb  = (f32x2){-bmd[1], bmd[0]};   /* i*(b-d) */                 \
        float rev_ = (float)(T1) * (1.0f / 1024.0f);                          \
        float s1_ = __builtin_amdgcn_sinf(rev_);                              \
        float c1_ = __builtin_amdgcn_cosf(rev_);                              \
        float c2_ = fmaf(-2.0f * s1_, s1_, 1.0f), s2_ = 2.0f * s1_ * c1_;     \
        float c3_ = c2_ * c1_ - s2_ * s1_, s3_ = s2_ * c1_ + c2_ * s1_;       \
        f32x2 u1 = amc + jb, u2 = apc - bpd, u3 = amc - jb;                   \
        O0 = apc + bpd;                                                       \
        O1 = (f32x2){u1[0] * c1_ - u1[1] * s1_, u1[0] * s1_ + u1[1] * c1_};   \
        O2 = (f32x2){u2[0] * c2_ - u2[1] * s2_, u2[0] * s2_ + u2[1] * c2_};   \
        O3 = (f32x2){u3[0] * c3_ - u3[1] * s3_, u3[0] * s3_ + u3[1] * c3_};   \
    }

// ================= kernel 1: 4 wave-local IFFTs per block =================
__global__ __launch_bounds__(256, 2) void ifft_wave4(
    const float* __restrict__ re, const float* __restrict__ im,
    const float* __restrict__ ola, unsigned short* __restrict__ frames) {
    __shared__ float L[4][1052];               // one 4.2KB plane buffer per wave

    const int tid = threadIdx.x;
    const int l   = tid & 63;
    const int w   = tid >> 6;
    const int r0  = (blockIdx.x * 4 + w) * 2;  // this wave's frame pair
    float* P = &L[w][0];

    const float* fre0 = re + (size_t)r0 * FREQ;
    const float* fim0 = im + (size_t)r0 * FREQ;
    const float* fre1 = fre0 + FREQ;
    const float* fim1 = fim0 + FREQ;

    // ---- stage 1 (S=1, vthreads l+64j): hermitian-packed global loads ----
    f32x2 s1v[4][4];
#pragma unroll
    for (int j = 0; j < 4; ++j) {
        f32x2 in[4];
#pragma unroll
        for (int k = 0; k < 4; ++k) {
            int n  = l + 64 * j + 256 * k;
            int mm = (n <= 512) ? n : (1024 - n);
            float A1 = fre0[mm], B1 = fim0[mm];
            float A2 = fre1[mm], B2 = fim1[mm];
            if (n == 0 || n == 512) { B1 = 0.0f; B2 = 0.0f; }  // DC/Nyq imag->0
            in[k] = (n <= 512) ? (f32x2){A1 - B2, B1 + A2}
                               : (f32x2){A1 + B2, A2 - B1};
        }
        BFLY(in[0], in[1], in[2], in[3], l + 64 * j,
             s1v[j][0], s1v[j][1], s1v[j][2], s1v[j][3]);
    }

    // ---- stage 2 (S=4, vthreads 4l+r, in-lane): out n = 16l + 4k + r ----
    f32x4 wRe[4], wIm[4];
#pragma unroll
    for (int r = 0; r < 4; ++r) {
        f32x2 o0, o1, o2, o3;
        BFLY(s1v[0][r], s1v[1][r], s1v[2][r], s1v[3][r], 4 * l, o0, o1, o2, o3);
        wRe[0][r] = o0[0]; wIm[0][r] = o0[1];
        wRe[1][r] = o1[0]; wIm[1][r] = o1[1];
        wRe[2][r] = o2[0]; wIm[2][r] = o2[1];
        wRe[3][r] = o3[0]; wIm[3][r] = o3[1];
    }

    // ---- exchange 1, Re plane: write b128 (slot 16l+4k+8*(l>>4)), read b32 ----
    {
        const int wb = 16 * l + 8 * (l >> 4);
#pragma unroll
        for (int k = 0; k < 4; ++k) *(f32x4*)&P[wb + 4 * k] = wRe[k];
    }
    DSYNC();
    float rr[4][4], ri[4][4];
#pragma unroll
    for (int j = 0; j < 4; ++j)
#pragma unroll
        for (int k = 0; k < 4; ++k) rr[j][k] = P[l + 64 * j + 264 * k];
    DSYNC();   // Re reads retired before Im overwrites (WAR)
    {
        const int wb = 16 * l + 8 * (l >> 4);
#pragma unroll
        for (int k = 0; k < 4; ++k) *(f32x4*)&P[wb + 4 * k] = wIm[k];
    }
    DSYNC();
#pragma unroll
    for (int j = 0; j < 4; ++j)
#pragma unroll
        for (int k = 0; k < 4; ++k) ri[j][k] = P[l + 64 * j + 264 * k];
    DSYNC();   // Im reads retired before exchange-2 overwrites

    // ---- stage 3 (S=16, vthreads l+64j) ----
    f32x2 s3v[4][4];
#pragma unroll
    for (int j = 0; j < 4; ++j) {
        f32x2 a = (f32x2){rr[j][0], ri[j][0]};
        f32x2 b = (f32x2){rr[j][1], ri[j][1]};
        f32x2 c = (f32x2){rr[j][2], ri[j][2]};
        f32x2 d = (f32x2){rr[j][3], ri[j][3]};
        BFLY(a, b, c, d, (((l + 64 * j) >> 4) << 4),
             s3v[j][0], s3v[j][1], s3v[j][2], s3v[j][3]);
    }

    // ---- stage 4 (S=64, in-lane): out n = 256(l>>4)+(l&15)+16r+64k ----
    float eRe[4][4], eIm[4][4];   // [k][r]
#pragma unroll
    for (int r = 0; r < 4; ++r) {
        f32x2 o0, o1, o2, o3;
        BFLY(s3v[0][r], s3v[1][r], s3v[2][r], s3v[3][r], ((l >> 4) << 6),
             o0, o1, o2, o3);
        eRe[0][r] = o0[0]; eIm[0][r] = o0[1];
        eRe[1][r] = o1[0]; eIm[1][r] = o1[1];
        eRe[2][r] = o2[0]; eIm[2][r] = o2[1];
        eRe[3][r] = o3[0]; eIm[3][r] = o3[1];
    }

    // ---- exchange 2, Re plane: write b32 (slot n+8*(l>>4)), read b32 ----
    {
        const int wb = 256 * (l >> 4) + (l & 15) + 8 * (l >> 4);
#pragma unroll
        for (int k = 0; k < 4; ++k)
#pragma unroll
            for (int r = 0; r < 4; ++r) P[wb + 16 * r + 64 * k] = eRe[k][r];
    }
    DSYNC();
    float yR[4][4], yI[4][4];     // [h][k]
#pragma unroll
    for (int h = 0; h < 4; ++h)
#pragma unroll
        for (int k = 0; k < 4; ++k) yR[h][k] = P[l + 64 * h + 264 * k];
    DSYNC();
    {
        const int wb = 256 * (l >> 4) + (l & 15) + 8 * (l >> 4);
#pragma unroll
        for (int k = 0; k < 4; ++k)
#pragma unroll
            for (int r = 0; r < 4; ++r) P[wb + 16 * r + 64 * k] = eIm[k][r];
    }
    DSYNC();
#pragma unroll
    for (int h = 0; h < 4; ++h)
#pragma unroll
        for (int k = 0; k < 4; ++k) yI[h][k] = P[l + 64 * h + 264 * k];
    DSYNC();

    // ---- stage 5 (S=256, unit twiddles) + hann + bf16 store ----
    unsigned short* fR = frames + (size_t)r0 * 1024;
    unsigned short* fI = fR + 1024;
#pragma unroll
    for (int h = 0; h < 4; ++h) {
        f32x2 a = (f32x2){yR[h][0], yI[h][0]};
        f32x2 b = (f32x2){yR[h][1], yI[h][1]};
        f32x2 c = (f32x2){yR[h][2], yI[h][2]};
        f32x2 d = (f32x2){yR[h][3], yI[h][3]};
        f32x2 apc = a + c, amc = a - c, bpd = b + d, bmd = b - d;
        f32x2 jb  = (f32x2){-bmd[1], bmd[0]};
        f32x2 y0 = apc + bpd, y1 = amc + jb, y2 = apc - bpd, y3 = amc - jb;
        int n0 = l + 64 * h;
        float h0 = sqrtf(ola[n0])       * (1.0f / 1024.0f);
        float h1 = sqrtf(ola[n0 + 256]) * (1.0f / 1024.0f);
        float h2 = sqrtf(ola[n0 + 512]) * (1.0f / 1024.0f);
        float h3 = sqrtf(ola[n0 + 768]) * (1.0f / 1024.0f);
        fR[n0]       = f2bf(y0[0] * h0);  fI[n0]       = f2bf(y0[1] * h0);
        fR[n0 + 256] = f2bf(y1[0] * h1);  fI[n0 + 256] = f2bf(y1[1] * h1);
        fR[n0 + 512] = f2bf(y2[0] * h2);  fI[n0 + 512] = f2bf(y2[1] * h2);
        fR[n0 + 768] = f2bf(y3[0] * h3);  fI[n0 + 768] = f2bf(y3[1] * h3);
    }
}

// ================= kernel 2: OLA gather, 4 samples/thread =================
__global__ __launch_bounds__(256) void ola_fold4(
    const unsigned short* __restrict__ frames, const float* __restrict__ ola,
    float* __restrict__ out) {
    const int col0 = (blockIdx.x * 256 + threadIdx.x) * 4;
    if (col0 >= OUTCOLS) return;
    const int b  = blockIdx.y;
    const int s  = col0 + 512;     // uncropped sample index
    const int g  = s >> 8;
    const int ls = s & 255;        // multiple of 4

    float a0 = 0.f, a1 = 0.f, a2 = 0.f, a3 = 0.f;
    float w0 = 0.f, w1 = 0.f, w2 = 0.f, w3 = 0.f;
#pragma unroll
    for (int j = 0; j < 4; ++j) {
        const int t = g - j;
        if (t >= 0 && t < NFRAMES) {
            uint2v u = *(const uint2v*)(frames + (((size_t)(b * NFRAMES + t)) << 10) + ls + 256 * j);
            a0 += __uint_as_float(u[0] << 16);
            a1 += __uint_as_float(u[0] & 0xffff0000u);
            a2 += __uint_as_float(u[1] << 16);
            a3 += __uint_as_float(u[1] & 0xffff0000u);
            f32x4 o = *(const f32x4*)(ola + ls + 256 * j);
            w0 += o[0]; w1 += o[1]; w2 += o[2]; w3 += o[3];
        }
    }
    f32x4 r = (f32x4){a0 / fmaxf(w0, 1e-11f), a1 / fmaxf(w1, 1e-11f),
                      a2 / fmaxf(w2, 1e-11f), a3 / fmaxf(w3, 1e-11f)};
    *(f32x4*)(out + (size_t)b * OUTCOLS + col0) = r;
}

// ================= last-resort naive fallback (round-1, proven) =================
__global__ __launch_bounds__(256) void istft_naive(
    const float* __restrict__ re, const float* __restrict__ im,
    const float* __restrict__ Wr, const float* __restrict__ Wi,
    const float* __restrict__ ola, float* __restrict__ out) {
    const int g = blockIdx.x + 2, b = blockIdx.y, ls = threadIdx.x;
    __shared__ float s_fr[4][FREQ];
    __shared__ float s_fi[4][FREQ];
#pragma unroll
    for (int jj = 0; jj < 4; ++jj) {
        const int t = g - jj;
        const bool valid = (t >= 0 && t < NFRAMES);
        const size_t base = ((size_t)b * NFRAMES + (valid ? t : 0)) * FREQ;
        for (int k = ls; k < FREQ; k += 256) {
            const float f = (k == 0 || k == FREQ - 1) ? 1.0f : 2.0f;
            s_fr[jj][k] = valid ? re[base + k] * f : 0.0f;
            s_fi[jj][k] = valid ? im[base + k] * f : 0.0f;
        }
    }
    __syncthreads();
    const float* wr = Wr + ls;
    const float* wi = Wi + ls;
    float acc = 0.0f;
    for (int k = 0; k < FREQ; ++k) {
        const float* wrk = wr + (size_t)k * 1024;
        const float* wik = wi + (size_t)k * 1024;
#pragma unroll
        for (int jj = 0; jj < 4; ++jj) {
            acc = fmaf(wrk[jj * 256], s_fr[jj][k], acc);
            acc = fmaf(-wik[jj * 256], s_fi[jj][k], acc);
        }
    }
    float wsv = 0.0f;
#pragma unroll
    for (int jj = 0; jj < 4; ++jj) {
        const int t = g - jj;
        if (t >= 0 && t < NFRAMES) wsv += ola[ls + jj * 256];
    }
    wsv = fmaxf(wsv, 1e-11f);
    out[(size_t)b * OUTCOLS + (g * 256 + ls - 512)] = acc / wsv;
}

extern "C" void kernel_launch(void* const* d_in, const int* in_sizes, int n_in,
                              void* d_out, int out_size, void* d_ws, size_t ws_size,
                              hipStream_t stream) {
    const float* re  = (const float*)d_in[0];
    const float* im  = (const float*)d_in[1];
    const float* Wr  = (const float*)d_in[2];
    const float* Wi  = (const float*)d_in[3];
    const float* ola = (const float*)d_in[4];
    float* out = (float*)d_out;

    if (ws_size >= WS_NEED) {
        unsigned short* frames = (unsigned short*)d_ws;
        hipLaunchKernelGGL(ifft_wave4, dim3(2048), dim3(256), 0, stream,
                           re, im, ola, frames);
        hipLaunchKernelGGL(ola_fold4, dim3(512, BATCH), dim3(256), 0, stream,
                           frames, ola, out);
    } else {
        dim3 grid(2047, BATCH);
        hipLaunchKernelGGL(istft_naive, grid, dim3(256), 0, stream,
                           re, im, Wr, Wi, ola, out);
    }
}